// Round 4
// baseline (427.379 us; speedup 1.0000x reference)
//
#include <hip/hip_runtime.h>

#define NN 10000
#define EE 100000
#define CC 32
#define GG 64
#define EPSV 1e-5f
#define NB 8               // src nodes per fused block
#define SLOTS 1056         // 32*32 P-slots + 32 bias slots (w2r layout [i][slot])
#define HST 32             // h row stride: 32 floats = 128B, fully coalesced
#define PST 36             // P2 c-stride per o-row (c=0..31 data, 32 bias, 33..35 pad)
#define PNODE (32*PST)     // 1152 floats per node in LDS
#define HBLK ((EE+255)/256)// 391 hist blocks in k_pre
#define WBLK 160           // w2t blocks in k_pre: 5 per i, i=0..31

// ---------------- k_pre: degree histograms + weight transposes --------
__global__ __launch_bounds__(256) void k_pre(const int* __restrict__ ei,
        int* __restrict__ cnt, int* __restrict__ deg,
        const float* __restrict__ w2a, const float* __restrict__ b2a,
        const float* __restrict__ w2b, const float* __restrict__ b2b,
        float* __restrict__ w2r1, float* __restrict__ w2r2) {
    int blk = blockIdx.x;
    int t = threadIdx.x;
    if (blk < HBLK) {
        int e = blk * 256 + t;
        if (e < EE) {
            atomicAdd(&cnt[ei[EE + e]], 1);   // dst in-degree
            atomicAdd(&deg[ei[e]], 1);        // src out-degree
        }
    } else {
        int b2i = blk - HBLK;                 // 0..159
        int s = (b2i % 5) * 256 + t;
        int i = b2i / 5;
        if (s < SLOTS) {
            float va = (s < 1024) ? w2a[(s >> 5) * 1024 + i * 32 + (s & 31)]
                                  : b2a[i * 32 + (s - 1024)];
            float vb = (s < 1024) ? w2b[(s >> 5) * 1024 + i * 32 + (s & 31)]
                                  : b2b[i * 32 + (s - 1024)];
            w2r1[i * SLOTS + s] = va;
            w2r2[i * SLOTS + s] = vb;
        }
    }
}

// -------- dual exclusive scan: deg->rowptr/cursor (CSR) and cnt->colptr/ccursor (CSC) ----
__global__ __launch_bounds__(1024) void k_scan(const int* __restrict__ deg,
                                               const int* __restrict__ cnt,
                                               int* __restrict__ rowptr,
                                               int* __restrict__ cursor,
                                               int* __restrict__ colptr,
                                               int* __restrict__ ccursor) {
    __shared__ int buf[1024];
    int t = threadIdx.x;
    int base = t * 10;
    for (int pass = 0; pass < 2; pass++) {
        const int* src = pass ? cnt : deg;
        int* dst_p = pass ? colptr : rowptr;
        int* dst_c = pass ? ccursor : cursor;
        int v[10]; int s = 0;
        #pragma unroll
        for (int k = 0; k < 10; k++) {
            int idx = base + k;
            v[k] = (idx < NN) ? src[idx] : 0;
            s += v[k];
        }
        buf[t] = s;
        for (int off = 1; off < 1024; off <<= 1) {
            __syncthreads();
            int val = buf[t] + ((t >= off) ? buf[t - off] : 0);
            __syncthreads();
            buf[t] = val;
        }
        __syncthreads();
        int carry = (t > 0) ? buf[t - 1] : 0;
        #pragma unroll
        for (int k = 0; k < 10; k++) {
            int idx = base + k;
            if (idx < NN) { dst_p[idx] = carry; dst_c[idx] = carry; }
            carry += v[k];
        }
        if (t == 1023) dst_p[NN] = buf[1023];
        __syncthreads();   // buf reused next pass
    }
}

// ---------------- scatter + per-edge h (both layers), CSR order; CSC pos list ----------
__global__ __launch_bounds__(256) void k_scatter(const int* __restrict__ ei,
        const float* __restrict__ edge_attr,
        const float* __restrict__ w1a, const float* __restrict__ b1a,
        const float* __restrict__ w1b, const float* __restrict__ b1b,
        int* __restrict__ cursor, int* __restrict__ ccursor,
        int* __restrict__ msrc, int* __restrict__ cpos,
        float* __restrict__ hbuf1, float* __restrict__ hbuf2) {
    __shared__ float wsh[320];   // [0:128) w1a | [128:160) b1a | [160:288) w1b | [288:320) b1b
    int t = threadIdx.x;
    for (int s = t; s < 320; s += 256) {
        wsh[s] = (s < 128) ? w1a[s]
               : (s < 160) ? b1a[s - 128]
               : (s < 288) ? w1b[s - 160]
                           : b1b[s - 288];
    }
    __syncthreads();
    int e = blockIdx.x * 256 + t;
    if (e >= EE) return;
    int sn = ei[e];
    int dn = ei[EE + e];
    float4 a = *(const float4*)&edge_attr[(size_t)e * 4];
    int pos = atomicAdd(&cursor[sn], 1);
    msrc[pos] = sn;
    int cp = atomicAdd(&ccursor[dn], 1);
    cpos[cp] = pos;
    float h1v[32], h2v[32];
    #pragma unroll
    for (int o = 0; o < 32; o++) {
        h1v[o] = fmaxf(a.x * wsh[o]       + a.y * wsh[32 + o]  + a.z * wsh[64 + o]  + a.w * wsh[96 + o]  + wsh[128 + o], 0.f);
        h2v[o] = fmaxf(a.x * wsh[160 + o] + a.y * wsh[192 + o] + a.z * wsh[224 + o] + a.w * wsh[256 + o] + wsh[288 + o], 0.f);
    }
    #pragma unroll
    for (int ob = 0; ob < 8; ob++) {
        *(float4*)&hbuf1[(size_t)pos * HST + 4 * ob] =
            make_float4(h1v[4 * ob], h1v[4 * ob + 1], h1v[4 * ob + 2], h1v[4 * ob + 3]);
        *(float4*)&hbuf2[(size_t)pos * HST + 4 * ob] =
            make_float4(h2v[4 * ob], h2v[4 * ob + 1], h2v[4 * ob + 2], h2v[4 * ob + 3]);
    }
}

// ---------------- fused NNConv: P in LDS + streaming edge pass, no atomics ------------
// R11: back to high-occupancy structure (LDS = xs+P2 only = 37,888B -> 4 blocks/CU).
// Phase B streams msrc+hbuf from global (linear, L2-friendly) with a 2-deep
// software pipeline (two named register sets, manually unrolled - no array copies),
// writes per-edge msg with plain coalesced stores. All addresses are functions of pos.
__global__ __launch_bounds__(256, 4) void k_fused3(const float* __restrict__ x,
        const float* __restrict__ hbuf,
        const float* __restrict__ w2r,
        const int* __restrict__ msrc, const int* __restrict__ rowptr,
        float* __restrict__ msg) {
    __shared__ float xs[NB][32];         // 1,024 B
    __shared__ float P2[NB * PNODE];     // 36,864 B  (total 37,888 -> 4 blocks/CU)
    int t = threadIdx.x;
    int o = t & 31;
    int cb = 4 * (t >> 5);               // base c (0,4,...,28)
    int n0 = blockIdx.x * NB;

    int ebase = rowptr[n0];
    int eend  = rowptr[n0 + NB];

    xs[t >> 5][t & 31] = x[n0 * 32 + t];
    __syncthreads();

    // ---- Phase A: P2[n][o][c] = sum_i x[n,i] * w2r[i][c*32+o] ----
    {
        float acc[4][NB];
        #pragma unroll
        for (int k = 0; k < 4; k++)
            #pragma unroll
            for (int n = 0; n < NB; n++) acc[k][n] = 0.f;
        #pragma unroll
        for (int j = 0; j < 8; j++) {
            float wk[4][4];
            #pragma unroll
            for (int r = 0; r < 4; r++)
                #pragma unroll
                for (int k = 0; k < 4; k++)
                    wk[r][k] = w2r[(4 * j + r) * SLOTS + (cb + k) * 32 + o];
            #pragma unroll
            for (int n = 0; n < NB; n++) {
                float4 xq = *(const float4*)&xs[n][4 * j];
                #pragma unroll
                for (int k = 0; k < 4; k++)
                    acc[k][n] += xq.x * wk[0][k] + xq.y * wk[1][k]
                               + xq.z * wk[2][k] + xq.w * wk[3][k];
            }
        }
        #pragma unroll
        for (int n = 0; n < NB; n++) {
            float4 st = make_float4(acc[0][n], acc[1][n], acc[2][n], acc[3][n]);
            *(float4*)&P2[n * PNODE + o * PST + cb] = st;
        }
    }
    if (t < 32) {
        float wb[32];
        #pragma unroll
        for (int i = 0; i < 32; i++) wb[i] = w2r[i * SLOTS + 1024 + t];
        #pragma unroll
        for (int n = 0; n < NB; n++) {
            float b = 0.f;
            #pragma unroll
            for (int j = 0; j < 8; j++) {
                float4 xq = *(const float4*)&xs[n][4 * j];
                b += xq.x * wb[4 * j] + xq.y * wb[4 * j + 1]
                   + xq.z * wb[4 * j + 2] + xq.w * wb[4 * j + 3];
            }
            *(float4*)&P2[n * PNODE + t * PST + 32] = make_float4(b, 0.f, 0.f, 0.f);
        }
    }
    __syncthreads();

    // ---- Phase B: 32-lane group per edge, 2-deep pipeline (sets A and B) ----
    int grp = t >> 5;
    int pos = ebase + grp;

    int srcA = n0, srcB = n0;
    float4 hqA[8], hqB[8];
    if (pos < eend) {
        srcA = msrc[pos];
        const float* h0 = &hbuf[(size_t)pos * HST];
        #pragma unroll
        for (int b = 0; b < 8; b++) hqA[b] = *(const float4*)&h0[4 * b];
    }
    if (pos + 8 < eend) {
        srcB = msrc[pos + 8];
        const float* h1 = &hbuf[(size_t)(pos + 8) * HST];
        #pragma unroll
        for (int b = 0; b < 8; b++) hqB[b] = *(const float4*)&h1[4 * b];
    }

    while (pos < eend) {
        // ---- compute & store edge at pos (set A); prefetch pos+16 into A ----
        {
            const float* Pn = &P2[(srcA - n0) * PNODE + o * PST];
            float m = Pn[32];
            #pragma unroll
            for (int b = 0; b < 8; b++) {
                float4 pq = *(const float4*)&Pn[4 * b];
                m += hqA[b].x * pq.x + hqA[b].y * pq.y + hqA[b].z * pq.z + hqA[b].w * pq.w;
            }
            msg[(size_t)pos * 32 + o] = m;
            int p2 = pos + 16;
            if (p2 < eend) {
                srcA = msrc[p2];
                const float* hn = &hbuf[(size_t)p2 * HST];
                #pragma unroll
                for (int b = 0; b < 8; b++) hqA[b] = *(const float4*)&hn[4 * b];
            }
        }
        pos += 8;
        if (pos >= eend) break;
        // ---- compute & store edge at pos (set B); prefetch pos+16 into B ----
        {
            const float* Pn = &P2[(srcB - n0) * PNODE + o * PST];
            float m = Pn[32];
            #pragma unroll
            for (int b = 0; b < 8; b++) {
                float4 pq = *(const float4*)&Pn[4 * b];
                m += hqB[b].x * pq.x + hqB[b].y * pq.y + hqB[b].z * pq.z + hqB[b].w * pq.w;
            }
            msg[(size_t)pos * 32 + o] = m;
            int p3 = pos + 16;
            if (p3 < eend) {
                srcB = msrc[p3];
                const float* hn = &hbuf[(size_t)p3 * HST];
                #pragma unroll
                for (int b = 0; b < 8; b++) hqB[b] = *(const float4*)&hn[4 * b];
            }
        }
        pos += 8;
    }
}

// ---------------- combine: CSC gather of msg + x@root + bias -> BN -> ReLU ----------------
__global__ __launch_bounds__(256) void k_combine(const float* __restrict__ x_in,
        const float* __restrict__ msg,
        const int* __restrict__ colptr, const int* __restrict__ cpos,
        const float* __restrict__ root, const float* __restrict__ bias,
        const float* __restrict__ bng, const float* __restrict__ bnb,
        const float* __restrict__ bnm, const float* __restrict__ bnv,
        float* __restrict__ x_out, float* __restrict__ psum,
        const int* __restrict__ batch) {
    __shared__ float xs[8][32];
    __shared__ float vals[8][32];
    __shared__ int gb[8];
    int t = threadIdx.x;
    int n0 = blockIdx.x * 8;
    xs[t >> 5][t & 31] = x_in[n0 * 32 + t];
    __syncthreads();
    int k = t >> 5, o = t & 31, n = n0 + k;
    float r = bias[o];
    #pragma unroll
    for (int i = 0; i < 32; i++) r += xs[k][i] * root[i * 32 + o];
    // gather this node's in-edge messages (independent 128B reads, issued 8-deep)
    int jbase = colptr[n], jend = colptr[n + 1];
    float acc = 0.f;
    for (int jb = jbase; jb < jend; jb += 32) {
        int nrem = jend - jb;
        int lim = (nrem < 32) ? nrem : 32;
        int cv = 0;
        if (o < lim) cv = cpos[jb + o];
        for (int j = 0; j < lim; j += 8) {
            float v[8];
            #pragma unroll
            for (int q = 0; q < 8; q++) {
                if (j + q < lim) {
                    int cj = __shfl(cv, j + q, 32);
                    v[q] = msg[(size_t)cj * 32 + o];
                } else v[q] = 0.f;
            }
            #pragma unroll
            for (int q = 0; q < 8; q++) acc += v[q];
        }
    }
    float a = acc / fmaxf((float)(jend - jbase), 1.f);
    float val = a + r;
    val = (val - bnm[o]) * rsqrtf(bnv[o] + EPSV) * bng[o] + bnb[o];
    val = fmaxf(val, 0.f);
    if (x_out) {
        x_out[(size_t)n * 32 + o] = val;
    }
    if (psum) {
        vals[k][o] = val;
        if (o == 0) gb[k] = batch[n];
        __syncthreads();
        if (k == 0) {
            float pacc = vals[0][o];
            int g = gb[0];
            #pragma unroll
            for (int k2 = 1; k2 < 8; k2++) {
                if (gb[k2] == g) pacc += vals[k2][o];
                else {
                    atomicAdd(&psum[(size_t)g * 32 + o], pacc);
                    g = gb[k2]; pacc = vals[k2][o];
                }
            }
            atomicAdd(&psum[(size_t)g * 32 + o], pacc);
        }
    }
}

// ---------------- global mean pool + readout MLP ----------------
__global__ __launch_bounds__(256) void k_readout(const float* __restrict__ psum,
        const int* __restrict__ batch,
        const float* __restrict__ r1w, const float* __restrict__ r1b,
        const float* __restrict__ r2w, const float* __restrict__ r2b,
        float* __restrict__ out) {
    __shared__ float w1s[32 * 16];
    __shared__ float b1s[16];
    __shared__ float w2s[16];
    __shared__ float ps[GG * 32];
    int t = threadIdx.x;
    int cnt_g = 0;
    if (t < GG) {
        int lo = 0, hi = NN;
        while (lo < hi) { int m = (lo + hi) >> 1; if (batch[m] < t) lo = m + 1; else hi = m; }
        int lb = lo;
        lo = 0; hi = NN;
        while (lo < hi) { int m = (lo + hi) >> 1; if (batch[m] < t + 1) lo = m + 1; else hi = m; }
        cnt_g = lo - lb;
    }
    w1s[t] = r1w[t];
    w1s[t + 256] = r1w[t + 256];
    if (t < 16) { b1s[t] = r1b[t]; w2s[t] = r2w[t]; }
    #pragma unroll
    for (int i = 0; i < GG * 32 / 256; i++) ps[t + i * 256] = psum[t + i * 256];
    __syncthreads();
    if (t < GG) {
        float inv = 1.f / fmaxf((float)cnt_g, 1.f);
        float acc = r2b[0];
        #pragma unroll
        for (int j = 0; j < 16; j++) {
            float dot = 0.f;
            #pragma unroll
            for (int c = 0; c < 32; c++) dot += ps[t * 32 + c] * w1s[c * 16 + j];
            float z = dot * inv + b1s[j];
            acc += fmaxf(z, 0.f) * w2s[j];
        }
        out[t] = acc;
    }
}

extern "C" void kernel_launch(void* const* d_in, const int* in_sizes, int n_in,
                              void* d_out, int out_size, void* d_ws, size_t ws_size,
                              hipStream_t stream) {
    const float* x       = (const float*)d_in[0];
    const float* eattr   = (const float*)d_in[1];
    const float* e1_w1   = (const float*)d_in[2];
    const float* e1_b1   = (const float*)d_in[3];
    const float* e1_w2   = (const float*)d_in[4];
    const float* e1_b2   = (const float*)d_in[5];
    const float* root1   = (const float*)d_in[6];
    const float* bias1   = (const float*)d_in[7];
    const float* e2_w1   = (const float*)d_in[8];
    const float* e2_b1   = (const float*)d_in[9];
    const float* e2_w2   = (const float*)d_in[10];
    const float* e2_b2   = (const float*)d_in[11];
    const float* root2   = (const float*)d_in[12];
    const float* bias2   = (const float*)d_in[13];
    const float* bn1_g   = (const float*)d_in[14];
    const float* bn1_b   = (const float*)d_in[15];
    const float* bn1_m   = (const float*)d_in[16];
    const float* bn1_v   = (const float*)d_in[17];
    const float* bn2_g   = (const float*)d_in[18];
    const float* bn2_b   = (const float*)d_in[19];
    const float* bn2_m   = (const float*)d_in[20];
    const float* bn2_v   = (const float*)d_in[21];
    const float* r1_w    = (const float*)d_in[22];
    const float* r1_b    = (const float*)d_in[23];
    const float* r2_w    = (const float*)d_in[24];
    const float* r2_b    = (const float*)d_in[25];
    const int*   ei      = (const int*)d_in[26];
    const int*   batch   = (const int*)d_in[27];

    // workspace layout (bytes)
    char* ws = (char*)d_ws;
    float* hbuf1  = (float*)(ws);                   // 12,800,000
    float* hbuf2  = (float*)(ws + 12800000);        // 12,800,000
    float* w2r1   = (float*)(ws + 25600000);        // 135,168
    float* w2r2   = (float*)(ws + 25735168);        // 135,168
    float* msg    = (float*)(ws + 25870336);        // 12,800,000
    // ---- zero region start (88,192 B) ----
    int*   cnt    = (int*)  (ws + 38670336);        // 40,000
    int*   deg    = (int*)  (ws + 38710336);        // 40,000
    float* psum   = (float*)(ws + 38750336);        // 8,192
    // ---- zero region end ----
    float* xmid   = (float*)(ws + 38758528);        // 1,280,000
    int*   rowptr = (int*)  (ws + 40038528);        // 40,064
    int*   cursor = (int*)  (ws + 40078592);        // 40,000
    int*   colptr = (int*)  (ws + 40118592);        // 40,064
    int*   ccursor= (int*)  (ws + 40158656);        // 40,000
    int*   msrc   = (int*)  (ws + 40198656);        // 400,000
    int*   cpos   = (int*)  (ws + 40598656);        // 400,000
    // total ~41.0 MB

    hipMemsetAsync(ws + 38670336, 0, 88192, stream);   // cnt+deg+psum only

    // degree hists + weight transposes
    k_pre<<<HBLK + WBLK, 256, 0, stream>>>(ei, cnt, deg,
                                           e1_w2, e1_b2, e2_w2, e2_b2, w2r1, w2r2);
    // dual scan: CSR (deg) + CSC (cnt)
    k_scan<<<1, 1024, 0, stream>>>(deg, cnt, rowptr, cursor, colptr, ccursor);
    // CSR slot + msrc + h rows + CSC position list, one pass
    k_scatter<<<(EE + 255) / 256, 256, 0, stream>>>(ei, eattr,
                                                    e1_w1, e1_b1, e2_w1, e2_b1,
                                                    cursor, ccursor, msrc, cpos,
                                                    hbuf1, hbuf2);

    // ---- layer 1 ----
    k_fused3<<<NN / NB, 256, 0, stream>>>(x, hbuf1, w2r1, msrc, rowptr, msg);
    k_combine<<<NN / 8, 256, 0, stream>>>(x, msg, colptr, cpos, root1, bias1,
                                          bn1_g, bn1_b, bn1_m, bn1_v,
                                          xmid, nullptr, batch);

    // ---- layer 2 ----
    k_fused3<<<NN / NB, 256, 0, stream>>>(xmid, hbuf2, w2r2, msrc, rowptr, msg);
    k_combine<<<NN / 8, 256, 0, stream>>>(xmid, msg, colptr, cpos, root2, bias2,
                                          bn2_g, bn2_b, bn2_m, bn2_v,
                                          nullptr, psum, batch);

    // ---- pool + readout ----
    k_readout<<<1, 256, 0, stream>>>(psum, batch, r1_w, r1_b, r2_w, r2_b, (float*)d_out);
}

// Round 5
// 255.006 us; speedup vs baseline: 1.6760x; 1.6760x over previous
//
#include <hip/hip_runtime.h>

#define NN 10000
#define EE 100000
#define CC 32
#define GG 64
#define EPSV 1e-5f
#define NB 8               // src nodes per fused block
#define SLOTS 1056         // 32*32 P-slots + 32 bias slots (w2r layout [i][slot])
#define PST 36             // P2 c-stride per o-row (c=0..31 data, 32 bias, 33..35 pad)
#define PNODE (32*PST)     // 1152 floats per node in LDS
#define HBLK ((EE+255)/256)// 391 hist blocks in k_pre
#define WBLK 160           // w2t blocks in k_pre: 5 per i, i=0..31

// ---------------- k_pre: degree histograms + weight transposes --------
__global__ __launch_bounds__(256) void k_pre(const int* __restrict__ ei,
        int* __restrict__ cnt, int* __restrict__ deg,
        const float* __restrict__ w2a, const float* __restrict__ b2a,
        const float* __restrict__ w2b, const float* __restrict__ b2b,
        float* __restrict__ w2r1, float* __restrict__ w2r2) {
    int blk = blockIdx.x;
    int t = threadIdx.x;
    if (blk < HBLK) {
        int e = blk * 256 + t;
        if (e < EE) {
            atomicAdd(&cnt[ei[EE + e]], 1);   // dst in-degree
            atomicAdd(&deg[ei[e]], 1);        // src out-degree
        }
    } else {
        int b2i = blk - HBLK;                 // 0..159
        int s = (b2i % 5) * 256 + t;
        int i = b2i / 5;
        if (s < SLOTS) {
            float va = (s < 1024) ? w2a[(s >> 5) * 1024 + i * 32 + (s & 31)]
                                  : b2a[i * 32 + (s - 1024)];
            float vb = (s < 1024) ? w2b[(s >> 5) * 1024 + i * 32 + (s & 31)]
                                  : b2b[i * 32 + (s - 1024)];
            w2r1[i * SLOTS + s] = va;
            w2r2[i * SLOTS + s] = vb;
        }
    }
}

// -------- dual exclusive scan: deg->rowptr/cursor (CSR) and cnt->colptr/ccursor (CSC) ----
__global__ __launch_bounds__(1024) void k_scan(const int* __restrict__ deg,
                                               const int* __restrict__ cnt,
                                               int* __restrict__ rowptr,
                                               int* __restrict__ cursor,
                                               int* __restrict__ colptr,
                                               int* __restrict__ ccursor) {
    __shared__ int buf[1024];
    int t = threadIdx.x;
    int base = t * 10;
    for (int pass = 0; pass < 2; pass++) {
        const int* src = pass ? cnt : deg;
        int* dst_p = pass ? colptr : rowptr;
        int* dst_c = pass ? ccursor : cursor;
        int v[10]; int s = 0;
        #pragma unroll
        for (int k = 0; k < 10; k++) {
            int idx = base + k;
            v[k] = (idx < NN) ? src[idx] : 0;
            s += v[k];
        }
        buf[t] = s;
        for (int off = 1; off < 1024; off <<= 1) {
            __syncthreads();
            int val = buf[t] + ((t >= off) ? buf[t - off] : 0);
            __syncthreads();
            buf[t] = val;
        }
        __syncthreads();
        int carry = (t > 0) ? buf[t - 1] : 0;
        #pragma unroll
        for (int k = 0; k < 10; k++) {
            int idx = base + k;
            if (idx < NN) { dst_p[idx] = carry; dst_c[idx] = carry; }
            carry += v[k];
        }
        if (t == 1023) dst_p[NN] = buf[1023];
        __syncthreads();   // buf reused next pass
    }
}

// ---------------- scatter: CSR slots + edge_attr in CSR order + CSC pos list ----------
// R12: h is no longer precomputed (k_fused3 recomputes it from eattr, 4 FMA/component).
// This kernel now only permutes: msrc[pos]=src, ea_csr[pos]=edge_attr[e], cpos list.
__global__ void k_scatter(const int* __restrict__ ei,
        const float* __restrict__ edge_attr,
        int* __restrict__ cursor, int* __restrict__ ccursor,
        int* __restrict__ msrc, int* __restrict__ cpos,
        float4* __restrict__ ea_csr) {
    int e = blockIdx.x * 256 + threadIdx.x;
    if (e >= EE) return;
    int sn = ei[e];
    int dn = ei[EE + e];
    float4 a = *(const float4*)&edge_attr[(size_t)e * 4];
    int pos = atomicAdd(&cursor[sn], 1);
    msrc[pos] = sn;
    ea_csr[pos] = a;
    int cp = atomicAdd(&ccursor[dn], 1);
    cpos[cp] = pos;
}

// ---------------- fused NNConv: P in LDS + on-the-fly h + in-wave LDS transpose -------
// R12: Phase B global traffic = 20B/edge (ea_csr 16B + msrc 4B), both pos-addressed,
// 1-deep prefetch. h recomputed per lane (5 FMA) -> LDS transpose slot (1KB) ->
// broadcast float4 reads. msg written with plain coalesced stores. No atomics.
__global__ __launch_bounds__(256, 3) void k_fused3(const float* __restrict__ x,
        const float4* __restrict__ ea_csr,
        const float* __restrict__ w1, const float* __restrict__ b1,
        const float* __restrict__ w2r,
        const int* __restrict__ msrc, const int* __restrict__ rowptr,
        float* __restrict__ msg) {
    __shared__ float xs[NB][32];         // 1,024 B
    __shared__ float P2[NB * PNODE];     // 36,864 B
    __shared__ float shx[8][32];         // 1,024 B  (total 38,912 -> 4 blocks/CU)
    int t = threadIdx.x;
    int o = t & 31;
    int cb = 4 * (t >> 5);               // base c (0,4,...,28)
    int n0 = blockIdx.x * NB;

    int ebase = rowptr[n0];
    int eend  = rowptr[n0 + NB];
    int grp = t >> 5;

    // per-lane h weights (column o of W1, bias o) — L2-hot, loaded once
    float wc0 = w1[o], wc1 = w1[32 + o], wc2 = w1[64 + o], wc3 = w1[96 + o];
    float bb  = b1[o];

    // prefetch first edge's attr+src (lives in regs through Phase A)
    int pos = ebase + grp;
    float4 aC = make_float4(0.f, 0.f, 0.f, 0.f);
    int srcC = n0;
    if (pos < eend) {
        aC = ea_csr[pos];
        srcC = msrc[pos];
    }

    xs[t >> 5][t & 31] = x[n0 * 32 + t];
    __syncthreads();

    // ---- Phase A: P2[n][o][c] = sum_i x[n,i] * w2r[i][c*32+o] ----
    {
        float acc[4][NB];
        #pragma unroll
        for (int k = 0; k < 4; k++)
            #pragma unroll
            for (int n = 0; n < NB; n++) acc[k][n] = 0.f;
        #pragma unroll
        for (int j = 0; j < 8; j++) {
            float wk[4][4];
            #pragma unroll
            for (int r = 0; r < 4; r++)
                #pragma unroll
                for (int k = 0; k < 4; k++)
                    wk[r][k] = w2r[(4 * j + r) * SLOTS + (cb + k) * 32 + o];
            #pragma unroll
            for (int n = 0; n < NB; n++) {
                float4 xq = *(const float4*)&xs[n][4 * j];
                #pragma unroll
                for (int k = 0; k < 4; k++)
                    acc[k][n] += xq.x * wk[0][k] + xq.y * wk[1][k]
                               + xq.z * wk[2][k] + xq.w * wk[3][k];
            }
        }
        #pragma unroll
        for (int n = 0; n < NB; n++) {
            float4 st = make_float4(acc[0][n], acc[1][n], acc[2][n], acc[3][n]);
            *(float4*)&P2[n * PNODE + o * PST + cb] = st;
        }
    }
    if (t < 32) {
        float wb[32];
        #pragma unroll
        for (int i = 0; i < 32; i++) wb[i] = w2r[i * SLOTS + 1024 + t];
        #pragma unroll
        for (int n = 0; n < NB; n++) {
            float b = 0.f;
            #pragma unroll
            for (int j = 0; j < 8; j++) {
                float4 xq = *(const float4*)&xs[n][4 * j];
                b += xq.x * wb[4 * j] + xq.y * wb[4 * j + 1]
                   + xq.z * wb[4 * j + 2] + xq.w * wb[4 * j + 3];
            }
            *(float4*)&P2[n * PNODE + t * PST + 32] = make_float4(b, 0.f, 0.f, 0.f);
        }
    }
    __syncthreads();

    // ---- Phase B: 32-lane group per edge; h recomputed + in-wave LDS transpose ----
    while (pos < eend) {
        int pn = pos + 8;
        float4 aN = aC; int srcN = srcC;
        if (pn < eend) {                        // 1-deep prefetch (pos-addressed)
            aN = ea_csr[pn];
            srcN = msrc[pn];
        }
        // own h component -> group's transpose slot
        float h = fmaxf(aC.x * wc0 + aC.y * wc1 + aC.z * wc2 + aC.w * wc3 + bb, 0.f);
        shx[grp][o] = h;
        asm volatile("" ::: "memory");          // keep write before reads (HW: in-order DS per wave)
        const float* Pn = &P2[(srcC - n0) * PNODE + o * PST];
        float m = Pn[32];                       // bias slot
        #pragma unroll
        for (int b = 0; b < 8; b++) {
            float4 hx = *(const float4*)&shx[grp][4 * b];   // broadcast, conflict-free
            float4 pq = *(const float4*)&Pn[4 * b];
            m += hx.x * pq.x + hx.y * pq.y + hx.z * pq.z + hx.w * pq.w;
        }
        msg[(size_t)pos * 32 + o] = m;          // coalesced 128B store per group
        asm volatile("" ::: "memory");          // next iter's shx write stays below these reads
        pos = pn; aC = aN; srcC = srcN;
    }
}

// ---------------- combine: CSC gather of msg + x@root + bias -> BN -> ReLU ----------------
__global__ __launch_bounds__(256) void k_combine(const float* __restrict__ x_in,
        const float* __restrict__ msg,
        const int* __restrict__ colptr, const int* __restrict__ cpos,
        const float* __restrict__ root, const float* __restrict__ bias,
        const float* __restrict__ bng, const float* __restrict__ bnb,
        const float* __restrict__ bnm, const float* __restrict__ bnv,
        float* __restrict__ x_out, float* __restrict__ psum,
        const int* __restrict__ batch) {
    __shared__ float xs[8][32];
    __shared__ float vals[8][32];
    __shared__ int gb[8];
    int t = threadIdx.x;
    int n0 = blockIdx.x * 8;
    xs[t >> 5][t & 31] = x_in[n0 * 32 + t];
    __syncthreads();
    int k = t >> 5, o = t & 31, n = n0 + k;
    float r = bias[o];
    #pragma unroll
    for (int i = 0; i < 32; i++) r += xs[k][i] * root[i * 32 + o];
    // gather this node's in-edge messages (independent 128B reads, issued 8-deep)
    int jbase = colptr[n], jend = colptr[n + 1];
    float acc = 0.f;
    for (int jb = jbase; jb < jend; jb += 32) {
        int nrem = jend - jb;
        int lim = (nrem < 32) ? nrem : 32;
        int cv = 0;
        if (o < lim) cv = cpos[jb + o];
        for (int j = 0; j < lim; j += 8) {
            float v[8];
            #pragma unroll
            for (int q = 0; q < 8; q++) {
                if (j + q < lim) {
                    int cj = __shfl(cv, j + q, 32);
                    v[q] = msg[(size_t)cj * 32 + o];
                } else v[q] = 0.f;
            }
            #pragma unroll
            for (int q = 0; q < 8; q++) acc += v[q];
        }
    }
    float a = acc / fmaxf((float)(jend - jbase), 1.f);
    float val = a + r;
    val = (val - bnm[o]) * rsqrtf(bnv[o] + EPSV) * bng[o] + bnb[o];
    val = fmaxf(val, 0.f);
    if (x_out) {
        x_out[(size_t)n * 32 + o] = val;
    }
    if (psum) {
        vals[k][o] = val;
        if (o == 0) gb[k] = batch[n];
        __syncthreads();
        if (k == 0) {
            float pacc = vals[0][o];
            int g = gb[0];
            #pragma unroll
            for (int k2 = 1; k2 < 8; k2++) {
                if (gb[k2] == g) pacc += vals[k2][o];
                else {
                    atomicAdd(&psum[(size_t)g * 32 + o], pacc);
                    g = gb[k2]; pacc = vals[k2][o];
                }
            }
            atomicAdd(&psum[(size_t)g * 32 + o], pacc);
        }
    }
}

// ---------------- global mean pool + readout MLP ----------------
__global__ __launch_bounds__(256) void k_readout(const float* __restrict__ psum,
        const int* __restrict__ batch,
        const float* __restrict__ r1w, const float* __restrict__ r1b,
        const float* __restrict__ r2w, const float* __restrict__ r2b,
        float* __restrict__ out) {
    __shared__ float w1s[32 * 16];
    __shared__ float b1s[16];
    __shared__ float w2s[16];
    __shared__ float ps[GG * 32];
    int t = threadIdx.x;
    int cnt_g = 0;
    if (t < GG) {
        int lo = 0, hi = NN;
        while (lo < hi) { int m = (lo + hi) >> 1; if (batch[m] < t) lo = m + 1; else hi = m; }
        int lb = lo;
        lo = 0; hi = NN;
        while (lo < hi) { int m = (lo + hi) >> 1; if (batch[m] < t + 1) lo = m + 1; else hi = m; }
        cnt_g = lo - lb;
    }
    w1s[t] = r1w[t];
    w1s[t + 256] = r1w[t + 256];
    if (t < 16) { b1s[t] = r1b[t]; w2s[t] = r2w[t]; }
    #pragma unroll
    for (int i = 0; i < GG * 32 / 256; i++) ps[t + i * 256] = psum[t + i * 256];
    __syncthreads();
    if (t < GG) {
        float inv = 1.f / fmaxf((float)cnt_g, 1.f);
        float acc = r2b[0];
        #pragma unroll
        for (int j = 0; j < 16; j++) {
            float dot = 0.f;
            #pragma unroll
            for (int c = 0; c < 32; c++) dot += ps[t * 32 + c] * w1s[c * 16 + j];
            float z = dot * inv + b1s[j];
            acc += fmaxf(z, 0.f) * w2s[j];
        }
        out[t] = acc;
    }
}

extern "C" void kernel_launch(void* const* d_in, const int* in_sizes, int n_in,
                              void* d_out, int out_size, void* d_ws, size_t ws_size,
                              hipStream_t stream) {
    const float* x       = (const float*)d_in[0];
    const float* eattr   = (const float*)d_in[1];
    const float* e1_w1   = (const float*)d_in[2];
    const float* e1_b1   = (const float*)d_in[3];
    const float* e1_w2   = (const float*)d_in[4];
    const float* e1_b2   = (const float*)d_in[5];
    const float* root1   = (const float*)d_in[6];
    const float* bias1   = (const float*)d_in[7];
    const float* e2_w1   = (const float*)d_in[8];
    const float* e2_b1   = (const float*)d_in[9];
    const float* e2_w2   = (const float*)d_in[10];
    const float* e2_b2   = (const float*)d_in[11];
    const float* root2   = (const float*)d_in[12];
    const float* bias2   = (const float*)d_in[13];
    const float* bn1_g   = (const float*)d_in[14];
    const float* bn1_b   = (const float*)d_in[15];
    const float* bn1_m   = (const float*)d_in[16];
    const float* bn1_v   = (const float*)d_in[17];
    const float* bn2_g   = (const float*)d_in[18];
    const float* bn2_b   = (const float*)d_in[19];
    const float* bn2_m   = (const float*)d_in[20];
    const float* bn2_v   = (const float*)d_in[21];
    const float* r1_w    = (const float*)d_in[22];
    const float* r1_b    = (const float*)d_in[23];
    const float* r2_w    = (const float*)d_in[24];
    const float* r2_b    = (const float*)d_in[25];
    const int*   ei      = (const int*)d_in[26];
    const int*   batch   = (const int*)d_in[27];

    // workspace layout (bytes)
    char* ws = (char*)d_ws;
    float*  w2r1   = (float*) (ws);                  // 135,168
    float*  w2r2   = (float*) (ws + 135168);         // 135,168
    float*  msg    = (float*) (ws + 270336);         // 12,800,000
    float4* ea_csr = (float4*)(ws + 13070336);       // 1,600,000
    // ---- zero region start (88,192 B) ----
    int*    cnt    = (int*)   (ws + 14670336);       // 40,000
    int*    deg    = (int*)   (ws + 14710336);       // 40,000
    float*  psum   = (float*) (ws + 14750336);       // 8,192
    // ---- zero region end ----
    float*  xmid   = (float*) (ws + 14758528);       // 1,280,000
    int*    rowptr = (int*)   (ws + 16038528);       // 40,064
    int*    cursor = (int*)   (ws + 16078592);       // 40,000
    int*    colptr = (int*)   (ws + 16118592);       // 40,064
    int*    ccursor= (int*)   (ws + 16158656);       // 40,000
    int*    msrc   = (int*)   (ws + 16198656);       // 400,000
    int*    cpos   = (int*)   (ws + 16598656);       // 400,000
    // total ~17.0 MB

    hipMemsetAsync(ws + 14670336, 0, 88192, stream);   // cnt+deg+psum only

    // degree hists + weight transposes
    k_pre<<<HBLK + WBLK, 256, 0, stream>>>(ei, cnt, deg,
                                           e1_w2, e1_b2, e2_w2, e2_b2, w2r1, w2r2);
    // dual scan: CSR (deg) + CSC (cnt)
    k_scan<<<1, 1024, 0, stream>>>(deg, cnt, rowptr, cursor, colptr, ccursor);
    // CSR slot + msrc + ea_csr + CSC position list, one light pass
    k_scatter<<<(EE + 255) / 256, 256, 0, stream>>>(ei, eattr,
                                                    cursor, ccursor, msrc, cpos,
                                                    ea_csr);

    // ---- layer 1 ----
    k_fused3<<<NN / NB, 256, 0, stream>>>(x, ea_csr, e1_w1, e1_b1, w2r1,
                                          msrc, rowptr, msg);
    k_combine<<<NN / 8, 256, 0, stream>>>(x, msg, colptr, cpos, root1, bias1,
                                          bn1_g, bn1_b, bn1_m, bn1_v,
                                          xmid, nullptr, batch);

    // ---- layer 2 ----
    k_fused3<<<NN / NB, 256, 0, stream>>>(xmid, ea_csr, e2_w1, e2_b1, w2r2,
                                          msrc, rowptr, msg);
    k_combine<<<NN / 8, 256, 0, stream>>>(xmid, msg, colptr, cpos, root2, bias2,
                                          bn2_g, bn2_b, bn2_m, bn2_v,
                                          nullptr, psum, batch);

    // ---- pool + readout ----
    k_readout<<<1, 256, 0, stream>>>(psum, batch, r1_w, r1_b, r2_w, r2_b, (float*)d_out);
}